// Round 9
// baseline (436.298 us; speedup 1.0000x reference)
//
#include <hip/hip_runtime.h>

#define N_USERS 60000
#define N_ITEMS 40000
#define N_TOTAL 100000
#define EMB 64
#define LN_EPS 1e-5f

#define KPS 512                                  // keys per super-bucket
#define NSUP ((N_TOTAL + KPS - 1) / KPS)         // 196
#define EPB 4096                                 // edges per build_l1 block
#define TR_ROWS 32                               // rows per transform block
#define XPITCH 68                                // x-tile pitch (floats)

// bf16 helpers
__device__ __forceinline__ float bf2f(unsigned short h)
{ return __uint_as_float(((unsigned)h) << 16); }
__device__ __forceinline__ unsigned short f2bf(float f)
{
    unsigned u = __float_as_uint(f);
    return (unsigned short)((u + 0x7FFFu + ((u >> 16) & 1u)) >> 16);
}
// packed-bf16 lane helpers: word = [bf_even | bf_odd<<16]
__device__ __forceinline__ float blo(unsigned w)
{ return __uint_as_float(w << 16); }
__device__ __forceinline__ float bhi(unsigned w)
{ return __uint_as_float(w & 0xFFFF0000u); }

// ---------------------------------------------------------------------------
// ego2[r,:] = c * filt[r] * (x[r,:] @ W) + x[r,:]   (bf16 output)
__global__ void transform_tile(const float* __restrict__ x,
                               const float* __restrict__ w_uu,
                               const float* __restrict__ filt_uu,
                               const float* __restrict__ par_uu,
                               const float* __restrict__ w_ii,
                               const float* __restrict__ filt_ii,
                               const float* __restrict__ par_ii,
                               unsigned short* __restrict__ out)
{
    __shared__ float Wls[EMB * EMB];             // 16 KB
    __shared__ float xs[TR_ROWS * XPITCH];       // 8.7 KB
    const int tid = threadIdx.x;
    const int r0 = blockIdx.x * TR_ROWS;
    const int itm = (r0 >= N_USERS);             // uniform per block
    const float* W  = itm ? w_ii : w_uu;
    const float* fb = itm ? filt_ii : filt_uu;
    const int foff  = itm ? N_USERS : 0;
    const float c   = itm ? par_ii[0] * par_ii[1] : par_uu[0] * par_uu[1];

    for (int i = tid; i < EMB * EMB / 4; i += 256)
        ((float4*)Wls)[i] = ((const float4*)W)[i];
    for (int i = tid; i < TR_ROWS * 16; i += 256) {
        const float4 v = ((const float4*)x)[r0 * 16 + i];
        *(float4*)&xs[(i >> 4) * XPITCH + (i & 15) * 4] = v;
    }
    __syncthreads();

    const int lane = tid & 63;
    const int wv = tid >> 6;
    const int rg = lane >> 4;
    const int j  = lane & 15;

#pragma unroll
    for (int it = 0; it < 2; ++it) {
        const int rl = wv * 8 + it * 4 + rg;
        const int row = r0 + rl;
        float4 acc = make_float4(0.f, 0.f, 0.f, 0.f);
#pragma unroll 8
        for (int k = 0; k < EMB; ++k) {
            const float xb = xs[rl * XPITCH + k];
            const float4 w4 = *(const float4*)&Wls[k * EMB + 4 * j];
            acc.x += xb * w4.x; acc.y += xb * w4.y;
            acc.z += xb * w4.z; acc.w += xb * w4.w;
        }
        const float cf = c * fb[row - foff];
        const float4 xv = *(const float4*)&xs[rl * XPITCH + 4 * j];
        ushort4 o;
        o.x = f2bf(cf * acc.x + xv.x);
        o.y = f2bf(cf * acc.y + xv.y);
        o.z = f2bf(cf * acc.z + xv.z);
        o.w = f2bf(cf * acc.w + xv.w);
        *(ushort4*)&out[(size_t)row * EMB + 4 * j] = o;
    }
}

// ---------------------------------------------------------------------------
// Super-bucket histograms for BOTH orderings. LDS-local then merge.
__global__ void hist_sup(const int* __restrict__ rows,
                         const int* __restrict__ cols,
                         int* __restrict__ cnt_r,
                         int* __restrict__ cnt_c, int nnz)
{
    __shared__ int hr[NSUP], hc[NSUP];
    const int tid = threadIdx.x;
    for (int i = tid; i < NSUP; i += 256) { hr[i] = 0; hc[i] = 0; }
    __syncthreads();
    for (int e = blockIdx.x * 256 + tid; e < nnz; e += gridDim.x * 256) {
        atomicAdd(&hr[rows[e] >> 9], 1);
        atomicAdd(&hc[cols[e] >> 9], 1);
    }
    __syncthreads();
    for (int i = tid; i < NSUP; i += 256) {
        if (hr[i]) atomicAdd(&cnt_r[i], hr[i]);
        if (hc[i]) atomicAdd(&cnt_c[i], hc[i]);
    }
}

// Exclusive scan of the NSUP counters. grid=2: block 0 = cols, 1 = rows.
__global__ void scan_sup(const int* __restrict__ cnt_c, int* __restrict__ base_c,
                         int* __restrict__ cur_c,
                         const int* __restrict__ cnt_r, int* __restrict__ base_r,
                         int* __restrict__ cur_r)
{
    const int* cnt = blockIdx.x ? cnt_r : cnt_c;
    int* base = blockIdx.x ? base_r : base_c;
    int* cur  = blockIdx.x ? cur_r  : cur_c;
    __shared__ int wsum[4];
    const int lane = threadIdx.x & 63;
    const int wv = threadIdx.x >> 6;
    const int i = threadIdx.x;
    const int v = (i < NSUP) ? cnt[i] : 0;
    int incl = v;
#pragma unroll
    for (int off = 1; off < 64; off <<= 1) {
        const int t = __shfl_up(incl, off, 64);
        if (lane >= off) incl += t;
    }
    if (lane == 63) wsum[wv] = incl;
    __syncthreads();
    int woff = 0;
    for (int w = 0; w < wv; ++w) woff += wsum[w];
    const int excl = woff + incl - v;
    if (i < NSUP) { base[i] = excl; cur[i] = excl; }
    if (i == 0) base[NSUP] = wsum[0] + wsum[1] + wsum[2] + wsum[3];
}

// ---------------------------------------------------------------------------
// Level 1, direct scatter: per-4096-edge block, histogram by super-bucket,
// reserve (block,sup) region with one global atomic, then write each edge
// straight to its region (no LDS stage). All writes for a region come from
// ONE CU -> lines fill in one L2 before eviction (round-4 lesson: locality
// needs block-local write windows, not shards).
__global__ void build_l1(const int* __restrict__ key,
                         const int* __restrict__ other,
                         const float* __restrict__ vals,
                         int* __restrict__ cursor,
                         int2* __restrict__ pairs1, int nnz)
{
    __shared__ int hist[NSUP];
    __shared__ int gbase[NSUP];
    __shared__ int lcur[NSUP];

    const int tid = threadIdx.x;
    const int e0 = blockIdx.x * EPB;
    const int ecnt = min(EPB, nnz - e0);

    for (int i = tid; i < NSUP; i += 256) hist[i] = 0;
    __syncthreads();

    int myk[16], myo[16];
    float myv[16];
#pragma unroll
    for (int i = 0; i < 16; ++i) {
        const int s = tid + i * 256;
        if (s < ecnt) {
            const int e = e0 + s;
            myk[i] = key[e]; myo[i] = other[e]; myv[i] = vals[e];
            atomicAdd(&hist[myk[i] >> 9], 1);
        } else myk[i] = -1;
    }
    __syncthreads();

    for (int i = tid; i < NSUP; i += 256) {
        const int v = hist[i];
        gbase[i] = v ? atomicAdd(&cursor[i], v) : 0;
        lcur[i] = 0;
    }
    __syncthreads();

#pragma unroll
    for (int i = 0; i < 16; ++i) {
        if (myk[i] >= 0) {
            const int g = myk[i] >> 9;
            const int o = atomicAdd(&lcur[g], 1);
            pairs1[gbase[g] + o] =
                make_int2(myo[i] | ((myk[i] & (KPS - 1)) << 20),
                          __float_as_int(myv[i]));
        }
    }
}

// Level 2: one 1024-thread block per super-bucket. Exact counting sort;
// emits per-key END offsets.
__global__ void sort_l2(const int* __restrict__ base,
                        const int2* __restrict__ pairs1,
                        int2* __restrict__ pairs2,
                        int* __restrict__ fine_ends)
{
    __shared__ int cnt[KPS];
    __shared__ int cur[KPS];
    __shared__ int csum[8];
    const int sup = blockIdx.x;
    const int beg = base[sup];
    const int end = base[sup + 1];
    const int tid = threadIdx.x;
    const int lane = tid & 63;
    const int wv = tid >> 6;                     // 0..15

    if (tid < KPS) cnt[tid] = 0;
    __syncthreads();
    for (int j = beg + tid; j < end; j += 1024)
        atomicAdd(&cnt[pairs1[j].x >> 20], 1);
    __syncthreads();

    int orig = 0;
    if (wv < 8) {
        const int i = wv * 64 + lane;
        const int v = cnt[i];
        orig = v;
        int incl = v;
#pragma unroll
        for (int off = 1; off < 64; off <<= 1) {
            const int u = __shfl_up(incl, off, 64);
            if (lane >= off) incl += u;
        }
        cnt[i] = incl;
        if (lane == 63) csum[wv] = incl;
    }
    __syncthreads();
    if (tid == 0) {
        int run = 0;
#pragma unroll
        for (int c = 0; c < 8; ++c) { const int t = csum[c]; csum[c] = run; run += t; }
    }
    __syncthreads();
    if (wv < 8) {
        const int i = wv * 64 + lane;
        const int incl_g = csum[wv] + cnt[i];
        cur[i] = incl_g - orig;
        const int k = sup * KPS + i;
        if (k < N_TOTAL) fine_ends[k] = beg + incl_g;
    }
    __syncthreads();

    for (int j = beg + tid; j < end; j += 1024) {
        const int2 p = pairs1[j];
        const int pos = beg + atomicAdd(&cur[p.x >> 20], 1);
        pairs2[pos] = p;
    }
}

// ---------------------------------------------------------------------------
// Pull step: 8 lanes per edge, 16 B/lane (uint4 = 8 packed bf16). One vmem
// instruction gathers 8 edges (1024 B) -> half the gather requests of the
// 16-lane/edge layout (which measured request-bound at ~78 us).
template <int U>
__device__ __forceinline__ void pull_step8(const int2* __restrict__ pairs, int j,
                                           const unsigned short* __restrict__ src,
                                           int l, float4& a0, float4& a1)
{
    int2 p[U];
#pragma unroll
    for (int u = 0; u < U; ++u) p[u] = pairs[j + 8 * u];
    uint4 s[U];
#pragma unroll
    for (int u = 0; u < U; ++u)
        s[u] = ((const uint4*)(src + (size_t)(p[u].x & 0xFFFFF) * EMB))[l];
#pragma unroll
    for (int u = 0; u < U; ++u) {
        const float v = __int_as_float(p[u].y);
        a0.x += v * blo(s[u].x); a0.y += v * bhi(s[u].x);
        a0.z += v * blo(s[u].y); a0.w += v * bhi(s[u].y);
        a1.x += v * blo(s[u].z); a1.y += v * bhi(s[u].z);
        a1.z += v * blo(s[u].w); a1.w += v * bhi(s[u].w);
    }
}

// Pass 1: dst bf16. 8 edge-groups x 8 lanes; lane owns cols 8l..8l+7.
__global__ void spmm_pull_bf16(const int* __restrict__ ends,
                               const int2* __restrict__ pairs,
                               const unsigned short* __restrict__ src,
                               unsigned short* __restrict__ dst, int nrows)
{
    const int lane = threadIdx.x & 63;
    const int wv = threadIdx.x >> 6;
    const int r = blockIdx.x * 4 + wv;
    if (r >= nrows) return;
    const int beg = (r == 0) ? 0 : ends[r - 1];
    const int end = ends[r];
    const int g = lane >> 3;                     // edge group 0..7
    const int l = lane & 7;                      // uint4 slot 0..7
    float4 a0 = make_float4(0.f, 0.f, 0.f, 0.f);
    float4 a1 = make_float4(0.f, 0.f, 0.f, 0.f);
    int j = beg + g;
    for (; j + 24 < end; j += 32) pull_step8<4>(pairs, j, src, l, a0, a1);
    for (; j < end; j += 8)       pull_step8<1>(pairs, j, src, l, a0, a1);
#pragma unroll
    for (int m = 8; m <= 32; m <<= 1) {
        a0.x += __shfl_xor(a0.x, m, 64); a0.y += __shfl_xor(a0.y, m, 64);
        a0.z += __shfl_xor(a0.z, m, 64); a0.w += __shfl_xor(a0.w, m, 64);
        a1.x += __shfl_xor(a1.x, m, 64); a1.y += __shfl_xor(a1.y, m, 64);
        a1.z += __shfl_xor(a1.z, m, 64); a1.w += __shfl_xor(a1.w, m, 64);
    }
    if (g == 0) {
        uint4 o;
        o.x = (unsigned)f2bf(a0.x) | ((unsigned)f2bf(a0.y) << 16);
        o.y = (unsigned)f2bf(a0.z) | ((unsigned)f2bf(a0.w) << 16);
        o.z = (unsigned)f2bf(a1.x) | ((unsigned)f2bf(a1.y) << 16);
        o.w = (unsigned)f2bf(a1.z) | ((unsigned)f2bf(a1.w) << 16);
        ((uint4*)(dst + (size_t)r * EMB))[l] = o;
    }
}

// Pass 2 fused with LayerNorm + residual.
__global__ void spmm_pull_ln(const int* __restrict__ ends,
                             const int2* __restrict__ pairs,
                             const unsigned short* __restrict__ src,
                             const float* __restrict__ ego,
                             const float* __restrict__ gamma,
                             const float* __restrict__ beta,
                             float* __restrict__ out, int nrows)
{
    const int lane = threadIdx.x & 63;
    const int wv = threadIdx.x >> 6;
    const int r = blockIdx.x * 4 + wv;
    if (r >= nrows) return;
    const int beg = (r == 0) ? 0 : ends[r - 1];
    const int end = ends[r];
    const int g = lane >> 3;
    const int l = lane & 7;
    float4 a0 = make_float4(0.f, 0.f, 0.f, 0.f);
    float4 a1 = make_float4(0.f, 0.f, 0.f, 0.f);
    int j = beg + g;
    for (; j + 24 < end; j += 32) pull_step8<4>(pairs, j, src, l, a0, a1);
    for (; j < end; j += 8)       pull_step8<1>(pairs, j, src, l, a0, a1);
#pragma unroll
    for (int m = 8; m <= 32; m <<= 1) {
        a0.x += __shfl_xor(a0.x, m, 64); a0.y += __shfl_xor(a0.y, m, 64);
        a0.z += __shfl_xor(a0.z, m, 64); a0.w += __shfl_xor(a0.w, m, 64);
        a1.x += __shfl_xor(a1.x, m, 64); a1.y += __shfl_xor(a1.y, m, 64);
        a1.z += __shfl_xor(a1.z, m, 64); a1.w += __shfl_xor(a1.w, m, 64);
    }
    // row statistics across the 8 col-groups (bits 0-2 of lane)
    float s  = a0.x + a0.y + a0.z + a0.w + a1.x + a1.y + a1.z + a1.w;
    float s2 = a0.x * a0.x + a0.y * a0.y + a0.z * a0.z + a0.w * a0.w
             + a1.x * a1.x + a1.y * a1.y + a1.z * a1.z + a1.w * a1.w;
#pragma unroll
    for (int m = 1; m <= 4; m <<= 1) {
        s  += __shfl_xor(s,  m, 64);
        s2 += __shfl_xor(s2, m, 64);
    }
    const float mu  = s * (1.0f / EMB);
    const float var = s2 * (1.0f / EMB) - mu * mu;
    const float inv = rsqrtf(var + LN_EPS);
    if (g == 0) {
        const float4 gmA = ((const float4*)gamma)[2 * l];
        const float4 gmB = ((const float4*)gamma)[2 * l + 1];
        const float4 btA = ((const float4*)beta)[2 * l];
        const float4 btB = ((const float4*)beta)[2 * l + 1];
        const float4 egA = ((const float4*)(ego + (size_t)r * EMB))[2 * l];
        const float4 egB = ((const float4*)(ego + (size_t)r * EMB))[2 * l + 1];
        float4 oA, oB;
        oA.x = (a0.x - mu) * inv * gmA.x + btA.x + egA.x;
        oA.y = (a0.y - mu) * inv * gmA.y + btA.y + egA.y;
        oA.z = (a0.z - mu) * inv * gmA.z + btA.z + egA.z;
        oA.w = (a0.w - mu) * inv * gmA.w + btA.w + egA.w;
        oB.x = (a1.x - mu) * inv * gmB.x + btB.x + egB.x;
        oB.y = (a1.y - mu) * inv * gmB.y + btB.y + egB.y;
        oB.z = (a1.z - mu) * inv * gmB.z + btB.z + egB.z;
        oB.w = (a1.w - mu) * inv * gmB.w + btB.w + egB.w;
        ((float4*)(out + (size_t)r * EMB))[2 * l]     = oA;
        ((float4*)(out + (size_t)r * EMB))[2 * l + 1] = oB;
    }
}

// ---------------------------------------------------------------------------
// Fallback (round-1) atomic scatter path, fp32, used only if ws too small.
__global__ void transform_kernel(const float* __restrict__ x,
                                 const float* __restrict__ W,
                                 const float* __restrict__ filt,
                                 const float* __restrict__ par,
                                 float* __restrict__ out, int nrows)
{
    __shared__ float Ws[EMB * EMB];
    const int tid = threadIdx.x;
    for (int i = tid; i < EMB * EMB; i += blockDim.x) Ws[i] = W[i];
    __syncthreads();
    const float c = par[0] * par[1];
    const int lane = tid & 63;
    const int wave = tid >> 6;
    const int r0 = blockIdx.x * 32;
    for (int rr = wave; rr < 32; rr += 4) {
        const int r = r0 + rr;
        if (r >= nrows) break;
        const float xv = x[(size_t)r * EMB + lane];
        float acc = 0.f;
#pragma unroll
        for (int k = 0; k < EMB; ++k) {
            const float xk = __shfl(xv, k, 64);
            acc += xk * Ws[k * EMB + lane];
        }
        out[(size_t)r * EMB + lane] = c * filt[r] * acc + xv;
    }
}

__global__ void spmm_scatter(const int* __restrict__ src_idx,
                             const int* __restrict__ dst_idx,
                             const float* __restrict__ vals,
                             const float* __restrict__ src,
                             float* __restrict__ dst, int nnz)
{
    const long long t = (long long)blockIdx.x * blockDim.x + threadIdx.x;
    const int e = (int)(t >> 4);
    const int l = (int)(t & 15);
    if (e >= nnz) return;
    const int s = src_idx[e];
    const int d = dst_idx[e];
    const float v = vals[e];
    const float4 xv = ((const float4*)(src + (size_t)s * EMB))[l];
    float* dp = dst + (size_t)d * EMB + l * 4;
    atomicAdd(dp + 0, v * xv.x);
    atomicAdd(dp + 1, v * xv.y);
    atomicAdd(dp + 2, v * xv.z);
    atomicAdd(dp + 3, v * xv.w);
}

__global__ void ln_residual(const float* y,
                            const float* __restrict__ ego,
                            const float* __restrict__ gamma,
                            const float* __restrict__ beta,
                            float* out, int nrows)
{
    const int lane = threadIdx.x & 63;
    const int wave = threadIdx.x >> 6;
    const int r = blockIdx.x * 4 + wave;
    if (r >= nrows) return;
    const float v = y[(size_t)r * EMB + lane];
    float s = v, s2 = v * v;
#pragma unroll
    for (int off = 32; off > 0; off >>= 1) {
        s  += __shfl_down(s,  off, 64);
        s2 += __shfl_down(s2, off, 64);
    }
    s  = __shfl(s,  0, 64);
    s2 = __shfl(s2, 0, 64);
    const float mu  = s * (1.0f / EMB);
    const float var = s2 * (1.0f / EMB) - mu * mu;
    const float inv = rsqrtf(var + LN_EPS);
    out[(size_t)r * EMB + lane] =
        (v - mu) * inv * gamma[lane] + beta[lane] + ego[(size_t)r * EMB + lane];
}

extern "C" void kernel_launch(void* const* d_in, const int* in_sizes, int n_in,
                              void* d_out, int out_size, void* d_ws, size_t ws_size,
                              hipStream_t stream)
{
    const float* ego     = (const float*)d_in[0];
    const int*   rows    = (const int*)  d_in[1];
    const int*   cols    = (const int*)  d_in[2];
    const float* vals    = (const float*)d_in[3];
    const float* w_uu    = (const float*)d_in[4];
    const float* filt_uu = (const float*)d_in[5];
    const float* par_uu  = (const float*)d_in[6];
    const float* w_ii    = (const float*)d_in[7];
    const float* filt_ii = (const float*)d_in[8];
    const float* par_ii  = (const float*)d_in[9];
    const float* gamma   = (const float*)d_in[10];
    const float* beta    = (const float*)d_in[11];
    float* out = (float*)d_out;
    const int nnz = in_sizes[1];

    const size_t emb_elems = (size_t)N_TOTAL * EMB;
    const size_t emb_bytes = emb_elems * sizeof(float);

    // Same bound as rounds 2-8 (proven available); actual use = 77.2 MB.
    const size_t need = 2 * emb_bytes + (size_t)nnz * sizeof(int2)
                        + 2 * (size_t)N_TOTAL * sizeof(int);

    const int rb = (N_TOTAL + 3) / 4;

    if (ws_size >= need) {
        // ---- fast path: two-level exact sort + bf16 pull, LN fused ------
        unsigned short* ego2b = (unsigned short*)d_ws;    // 12.8 MB
        unsigned short* hb    = ego2b + emb_elems;        // 12.8 MB
        int2*  pairs1    = (int2*)(hb + emb_elems);       // 25.6 MB
        int2*  pairs2    = pairs1 + nnz;                  // 25.6 MB
        int*   fine_ends = (int*)(pairs2 + nnz);          // 400 KB
        int*   cnt_c  = fine_ends + N_TOTAL;
        int*   cnt_r  = cnt_c + NSUP;
        int*   base_c = cnt_r + NSUP;
        int*   cur_c  = base_c + (NSUP + 1);
        int*   base_r = cur_c + NSUP;
        int*   cur_r  = base_r + (NSUP + 1);

        hipMemsetAsync(cnt_c, 0, 2 * NSUP * sizeof(int), stream);

        hist_sup<<<512, 256, 0, stream>>>(rows, cols, cnt_r, cnt_c, nnz);
        scan_sup<<<2, 256, 0, stream>>>(cnt_c, base_c, cur_c,
                                        cnt_r, base_r, cur_r);

        transform_tile<<<N_TOTAL / TR_ROWS, 256, 0, stream>>>(
            ego, w_uu, filt_uu, par_uu, w_ii, filt_ii, par_ii, ego2b);

        const int l1b = (nnz + EPB - 1) / EPB;

        // Pass 1: key = col, payload = row.  h[c] = sum val*ego2[r]  (bf16)
        build_l1<<<l1b, 256, 0, stream>>>(cols, rows, vals, cur_c, pairs1, nnz);
        sort_l2<<<NSUP, 1024, 0, stream>>>(base_c, pairs1, pairs2, fine_ends);
        spmm_pull_bf16<<<rb, 256, 0, stream>>>(fine_ends, pairs2, ego2b, hb,
                                               N_TOTAL);

        // Pass 2: key = row, payload = col.  out = LN(A h) + ego, fused.
        build_l1<<<l1b, 256, 0, stream>>>(rows, cols, vals, cur_r, pairs1, nnz);
        sort_l2<<<NSUP, 1024, 0, stream>>>(base_r, pairs1, pairs2, fine_ends);
        spmm_pull_ln<<<rb, 256, 0, stream>>>(fine_ends, pairs2, hb,
                                             ego, gamma, beta, out, N_TOTAL);
    } else {
        // ---------------- fallback: atomic scatter (round-1, fp32) -------
        float* ego2 = (float*)d_ws;
        float* h    = ego2 + emb_elems;
        hipMemsetAsync(h,   0, emb_bytes, stream);
        hipMemsetAsync(out, 0, emb_bytes, stream);

        transform_kernel<<<(N_USERS + 31) / 32, 256, 0, stream>>>(
            ego, w_uu, filt_uu, par_uu, ego2, N_USERS);
        transform_kernel<<<(N_ITEMS + 31) / 32, 256, 0, stream>>>(
            ego + (size_t)N_USERS * EMB, w_ii, filt_ii, par_ii,
            ego2 + (size_t)N_USERS * EMB, N_ITEMS);

        const long long thr = (long long)nnz * 16;
        const int sblocks = (int)((thr + 255) / 256);
        spmm_scatter<<<sblocks, 256, 0, stream>>>(rows, cols, vals, ego2, h, nnz);
        spmm_scatter<<<sblocks, 256, 0, stream>>>(cols, rows, vals, h, out, nnz);

        ln_residual<<<rb, 256, 0, stream>>>(out, ego, gamma, beta, out, N_TOTAL);
    }
}